// Round 10
// baseline (1496.582 us; speedup 1.0000x reference)
//
#include <hip/hip_runtime.h>
#include <hip/hip_bf16.h>
#include <cstddef>

// Problem dims (fixed)
#define BB 256
#define CC 512
#define SS 128      // FH*FW = 8*16
#define HH 512
#define VV 64
#define LL 24       // sequence length; steps = 23

typedef unsigned short ush;
typedef __attribute__((ext_vector_type(8))) short short8;
typedef __attribute__((ext_vector_type(4))) float f32x4;

__device__ __forceinline__ float wave_sum(float v) {
#pragma unroll
    for (int off = 32; off > 0; off >>= 1) v += __shfl_xor(v, off);
    return v;
}
__device__ __forceinline__ float wave_max(float v) {
#pragma unroll
    for (int off = 32; off > 0; off >>= 1) v = fmaxf(v, __shfl_xor(v, off));
    return v;
}
__device__ __forceinline__ float sigm(float x) { return 1.0f / (1.0f + expf(-x)); }
__device__ __forceinline__ ush f2bf(float f) {
    unsigned u = __float_as_uint(f);
    u += 0x7FFFu + ((u >> 16) & 1u);
    return (ush)(u >> 16);
}
__device__ __forceinline__ float bf2f(ush b) {
    return __uint_as_float(((unsigned)b) << 16);
}
__device__ __forceinline__ unsigned pack2(float a, float b) {
    return (unsigned)f2bf(a) | ((unsigned)f2bf(b) << 16);
}

// XCD-pinned tile decode, 512-block variant: consecutive block ids round-robin
// across the 8 XCDs; each XCD owns a fixed 64-col weight slice (4 n-tiles of
// 16) for ALL m-tiles, so the slice stays resident in that XCD's 4MiB L2
// (r8-proven mechanism). 512 blocks = 2 blocks/CU = 4 waves/SIMD (2x TLP).
__device__ __forceinline__ void xcd_tile(int bid, int& m0, int& n0) {
    int xcd = bid & 7;
    int j = bid >> 3;               // 0..63 within XCD
    int nt = xcd * 4 + (j & 3);     // 32 n-tiles of 16 cols
    int mt = j >> 2;                // 16 m-tiles of 16 rows
    m0 = mt * 16;
    n0 = nt * 16;
}

// ---------------------------------------------------------------------------
__global__ __launch_bounds__(256) void init_kernel(const float* __restrict__ init_state,
                                                   float* __restrict__ h0,
                                                   float* __restrict__ h1,
                                                   ush* __restrict__ h0b,
                                                   ush* __restrict__ h1b,
                                                   float* __restrict__ acc) {
    int idx = blockIdx.x * 256 + threadIdx.x;
    if (idx < BB * HH) {
        float a = init_state[idx & (HH - 1)];
        float b = init_state[HH + (idx & (HH - 1))];
        h0[idx] = a; h1[idx] = b;
        h0b[idx] = f2bf(a); h1b[idx] = f2bf(b);
    }
    if (idx < 2) acc[idx] = 0.0f;
}

// ---------------------------------------------------------------------------
// Multi-segment fp32->bf16 convert: all weight conversions in one launch.
struct CvArgs {
    const float* src[8];
    ush* dst[8];
    int end[8];    // cumulative block counts; each block = 256 float4
};
__global__ __launch_bounds__(256) void conv_multi(CvArgs A) {
    int blk = blockIdx.x;
    int s = 0;
    while (s < 7 && blk >= A.end[s]) s++;
    int base = s ? A.end[s - 1] : 0;
    int i = (blk - base) * 256 + threadIdx.x;
    float4 v = ((const float4*)A.src[s])[i];
    uint2 o;
    o.x = pack2(v.x, v.y);
    o.y = pack2(v.z, v.w);
    ((uint2*)A.dst[s])[i] = o;
}

// gather embeddings -> bf16: xall[(t*256+m)*512+:]
__global__ __launch_bounds__(128) void gather_kernel(const float* __restrict__ embed_w,
                                                     const int* __restrict__ seq,
                                                     ush* __restrict__ xall) {
    int item = blockIdx.x;           // t*256 + m
    int t = item >> 8, m = item & 255;
    int row = seq[m * LL + t];
    float4 v = ((const float4*)(embed_w + (size_t)row * HH))[threadIdx.x];
    uint2 o;
    o.x = pack2(v.x, v.y);
    o.y = pack2(v.z, v.w);
    ((uint2*)(xall + (size_t)item * HH))[threadIdx.x] = o;
}

// ---------------------------------------------------------------------------
// enc transpose+convert: enc fp32 [b][c=512][s=128] -> enc_t bf16 [b*128+s][c=512]
__global__ __launch_bounds__(256) void enc_conv(const float* __restrict__ enc,
                                                ush* __restrict__ enc_t) {
    int b = blockIdx.x, cg = blockIdx.y;
    int c0 = cg * 128;
    __shared__ ush tile[128][130];
    const float* src = enc + ((size_t)b * 512 + c0) * 128;
#pragma unroll
    for (int i = 0; i < 16; i++) {
        int lin = i * 256 + threadIdx.x;
        int cl = lin >> 5, s4 = lin & 31;
        float4 v = ((const float4*)(src + (size_t)cl * 128))[s4];
        tile[s4 * 4 + 0][cl] = f2bf(v.x);
        tile[s4 * 4 + 1][cl] = f2bf(v.y);
        tile[s4 * 4 + 2][cl] = f2bf(v.z);
        tile[s4 * 4 + 3][cl] = f2bf(v.w);
    }
    __syncthreads();
#pragma unroll
    for (int i = 0; i < 16; i++) {
        int lin = i * 256 + threadIdx.x;
        int sl = lin >> 5, c4 = lin & 31;
        ush a0 = tile[sl][c4 * 4 + 0], a1 = tile[sl][c4 * 4 + 1];
        ush a2 = tile[sl][c4 * 4 + 2], a3 = tile[sl][c4 * 4 + 3];
        uint2 o;
        o.x = (unsigned)a0 | ((unsigned)a1 << 16);
        o.y = (unsigned)a2 | ((unsigned)a3 << 16);
        ((uint2*)(enc_t + ((size_t)b * 128 + sl) * 512 + c0))[c4] = o;
    }
}

// ---------------------------------------------------------------------------
// Ws MFMA (r0 variant, 4x-proven fastest ~62us; do NOT replace with bf16-A
// variants — r7/r9 both regressed: this one is strided-BW-bound at 2.5TB/s
// and its many outstanding scalar loads self-hide latency).
// Block: 256m x 64n (4 waves x 64m). grid (128, 8).
__global__ __launch_bounds__(256) void ws_mfma(const float* __restrict__ enc,
                                               const ush* __restrict__ Wb,
                                               const float* __restrict__ bias,
                                               ush* __restrict__ Ws_bf) {
    int tid = threadIdx.x;
    int wave = tid >> 6, lane = tid & 63;
    int quad = lane >> 4, l16 = lane & 15;
    int m0 = blockIdx.x * 256 + wave * 64;
    int n0 = blockIdx.y * 64;
    int b = m0 >> 7;
    int s_base = m0 & 127;
    const float* eb = enc + (size_t)b * CC * SS;
    const ush* wp = Wb + (size_t)(n0 + l16) * 512 + quad * 8;
    f32x4 acc[4][4];
#pragma unroll
    for (int f = 0; f < 4; f++)
#pragma unroll
        for (int s = 0; s < 4; s++) acc[f][s] = (f32x4){0.f, 0.f, 0.f, 0.f};
    for (int k0 = 0; k0 < 512; k0 += 32) {
        short8 af[4], bfr[4];
#pragma unroll
        for (int f = 0; f < 4; f++) {
            int s = s_base + f * 16 + l16;
#pragma unroll
            for (int j = 0; j < 8; j++) {
                float v = eb[(size_t)(k0 + quad * 8 + j) * SS + s];
                af[f][j] = (short)f2bf(v);
            }
        }
#pragma unroll
        for (int s = 0; s < 4; s++)
            bfr[s] = *(const short8*)(wp + (size_t)s * 16 * 512 + k0);
#pragma unroll
        for (int f = 0; f < 4; f++)
#pragma unroll
            for (int s = 0; s < 4; s++)
                acc[f][s] = __builtin_amdgcn_mfma_f32_16x16x32_bf16(af[f], bfr[s], acc[f][s], 0, 0, 0);
    }
#pragma unroll
    for (int f = 0; f < 4; f++)
#pragma unroll
        for (int s = 0; s < 4; s++)
#pragma unroll
            for (int r = 0; r < 4; r++) {
                int m = m0 + f * 16 + quad * 4 + r;
                int n = n0 + s * 16 + l16;
                Ws_bf[(size_t)m * HH + n] = f2bf(acc[f][s][r] + bias[n]);
            }
}

// ---------------------------------------------------------------------------
// Single-fragment prefetched MFMA pipeline (NSTEP k-steps of 32, 16 out cols).
// Ring depth 8 for NSTEP>=8 (r9-proven loop gain). 2 loads + 1 MFMA per step.
template <int NSTEP>
__device__ __forceinline__ void segk1(const ush* __restrict__ ap,
                                      const ush* __restrict__ bp, f32x4& a0) {
    constexpr int RING = NSTEP >= 8 ? 8 : (NSTEP < 4 ? NSTEP : 4);
    short8 as[RING], bs[RING];
#pragma unroll
    for (int i = 0; i < RING; i++) {
        as[i] = *(const short8*)(ap + 32 * i);
        bs[i] = *(const short8*)(bp + 32 * i);
    }
#pragma unroll
    for (int i = 0; i < NSTEP; i++) {
        const int sl = i & (RING - 1);
        a0 = __builtin_amdgcn_mfma_f32_16x16x32_bf16(as[sl], bs[sl], a0, 0, 0, 0);
        if (i + RING < NSTEP) {
            as[sl] = *(const short8*)(ap + 32 * (i + RING));
            bs[sl] = *(const short8*)(bp + 32 * (i + RING));
        }
    }
}

// ---------------------------------------------------------------------------
// Fused GRU: 512 threads, 8 waves; block tile 16m x 16n; grid 512 (2/CU).
// 12 LDS slots: r = s0+s1+s2, z = s3+s4+s5, n_i = s6+s7, n_h = s8+s9+s10+s11.
struct GruArgs {
    const ush* xs[8][2];
    const ush* wb[8][2];
    int wst[8][2];
    int nks[8][2];     // 0, 4, 8, or 16 k-steps
    int slot[8][2];
    int zmask;         // slots to zero-fill
};

__global__ __launch_bounds__(512) void gru_fused(GruArgs A,
                                                 const float* __restrict__ h_prev,
                                                 const float* __restrict__ bih,
                                                 const float* __restrict__ bhh,
                                                 float* __restrict__ h_out,
                                                 ush* __restrict__ h_out_bf) {
    int tid = threadIdx.x;
    int wave = __builtin_amdgcn_readfirstlane(tid >> 6);
    int lane = tid & 63, quad = lane >> 4, l16 = lane & 15;
    int m0, n0;
    xcd_tile(blockIdx.x, m0, n0);
    __shared__ float gbuf[12][16][16];
    if (A.zmask && tid < 256) {
        int mi = tid >> 4, ni = tid & 15;
#pragma unroll
        for (int s = 0; s < 12; s++)
            if ((A.zmask >> s) & 1) gbuf[s][mi][ni] = 0.0f;
    }
    for (int e = 0; e < 2; e++) {
        int nks = A.nks[wave][e];
        if (nks == 0) continue;
        f32x4 a0 = (f32x4){0.f, 0.f, 0.f, 0.f};
        int wst = A.wst[wave][e];
        const ush* ap = A.xs[wave][e] + (size_t)(m0 + l16) * 512 + quad * 8;
        const ush* bp = A.wb[wave][e] + (size_t)(n0 + l16) * wst + quad * 8;
        if (nks == 16)     segk1<16>(ap, bp, a0);
        else if (nks == 8) segk1<8>(ap, bp, a0);
        else               segk1<4>(ap, bp, a0);
        int sl = A.slot[wave][e];
#pragma unroll
        for (int r = 0; r < 4; r++)
            gbuf[sl][quad * 4 + r][l16] = a0[r];
    }
    __syncthreads();
    if (tid < 256) {
        int mi = tid >> 4, ni = tid & 15;
        int n = n0 + ni;
        size_t off = (size_t)(m0 + mi) * HH + n;
        float r  = sigm(gbuf[0][mi][ni] + gbuf[1][mi][ni] + gbuf[2][mi][ni] +
                        bih[n] + bhh[n]);
        float zf = sigm(gbuf[3][mi][ni] + gbuf[4][mi][ni] + gbuf[5][mi][ni] +
                        bih[512 + n] + bhh[512 + n]);
        float na = tanhf(gbuf[6][mi][ni] + gbuf[7][mi][ni] + bih[1024 + n] +
                         r * (gbuf[8][mi][ni] + gbuf[9][mi][ni] +
                              gbuf[10][mi][ni] + gbuf[11][mi][ni] + bhh[1024 + n]));
        float hp = h_prev[off];
        float ho = (1.0f - zf) * na + zf * hp;
        h_out[off] = ho;
        h_out_bf[off] = f2bf(ho);
    }
}

// ---------------------------------------------------------------------------
// Fused fc: y = relu([ctx|h] @ fc_w.T + b). 512 thr, 8 waves x K=128 each.
// Block tile 16m x 16n; grid 512 (2/CU), XCD-pinned.
__global__ __launch_bounds__(512) void fc_fused(const ush* __restrict__ ctx,
                                                const ush* __restrict__ h,
                                                const ush* __restrict__ wFc,
                                                const float* __restrict__ bias,
                                                ush* __restrict__ y,
                                                ush* __restrict__ ys) {
    int tid = threadIdx.x;
    int wave = __builtin_amdgcn_readfirstlane(tid >> 6);
    int lane = tid & 63, quad = lane >> 4, l16 = lane & 15;
    int m0, n0;
    xcd_tile(blockIdx.x, m0, n0);
    const ush* X = (wave < 4) ? ctx : h;
    int q = wave & 3;
    f32x4 a0 = (f32x4){0.f, 0.f, 0.f, 0.f};
    const ush* ap = X + (size_t)(m0 + l16) * 512 + q * 128 + quad * 8;
    const ush* bp = wFc + (size_t)(n0 + l16) * 1024 + (wave >= 4 ? 512 : 0) + q * 128 + quad * 8;
    segk1<4>(ap, bp, a0);
    __shared__ float gbuf[8][16][16];
#pragma unroll
    for (int r = 0; r < 4; r++)
        gbuf[wave][quad * 4 + r][l16] = a0[r];
    __syncthreads();
    if (tid < 256) {
        int mi = tid >> 4, ni = tid & 15;
        int n = n0 + ni;
        float v = bias[n];
#pragma unroll
        for (int w = 0; w < 8; w++) v += gbuf[w][mi][ni];
        v = fmaxf(v, 0.0f);
        ush bb = f2bf(v);
        size_t off = (size_t)(m0 + mi) * HH + n;
        y[off] = bb;
        if (ys) ys[off] = bb;
    }
}

// ---------------------------------------------------------------------------
// Fused u: u = h @ U.T + Ub (fp32 out). 512 thr, 8 waves x K=64 each.
// Block tile 16m x 16n; grid 512 (2/CU), XCD-pinned.
__global__ __launch_bounds__(512) void u_fused(const ush* __restrict__ h,
                                               const ush* __restrict__ wU,
                                               const float* __restrict__ Ub,
                                               float* __restrict__ Uo) {
    int tid = threadIdx.x;
    int wave = __builtin_amdgcn_readfirstlane(tid >> 6);
    int lane = tid & 63, quad = lane >> 4, l16 = lane & 15;
    int m0, n0;
    xcd_tile(blockIdx.x, m0, n0);
    f32x4 a0 = (f32x4){0.f, 0.f, 0.f, 0.f};
    const ush* ap = h + (size_t)(m0 + l16) * 512 + wave * 64 + quad * 8;
    const ush* bp = wU + (size_t)(n0 + l16) * 512 + wave * 64 + quad * 8;
    segk1<2>(ap, bp, a0);
    __shared__ float gbuf[8][16][16];
#pragma unroll
    for (int r = 0; r < 4; r++)
        gbuf[wave][quad * 4 + r][l16] = a0[r];
    __syncthreads();
    if (tid < 256) {
        int mi = tid >> 4, ni = tid & 15;
        int n = n0 + ni;
        float v = Ub[n];
#pragma unroll
        for (int w = 0; w < 8; w++) v += gbuf[w][mi][ni];
        Uo[(size_t)(m0 + mi) * HH + n] = v;
    }
}

// ---------------------------------------------------------------------------
// Attention v3 (round-2 proven): 512 threads/block, one block per batch item.
__global__ __launch_bounds__(512) void attn3(const float* __restrict__ u,
                                             const float* __restrict__ vw,
                                             const ush* __restrict__ Ws_bf,
                                             const ush* __restrict__ enc_t,
                                             ush* __restrict__ ctx_bf) {
    int b = blockIdx.x;
    int tid = threadIdx.x;
    int wave = tid >> 6, lane = tid & 63;
    int hi = lane >> 4, li = lane & 15;
    __shared__ float a[SS];
    __shared__ float part[8][512];

    float ur[4][8], vr[4][8];
#pragma unroll
    for (int p = 0; p < 4; p++) {
        const float* up = u + (size_t)b * HH + p * 128 + li * 8;
        const float* vp = vw + p * 128 + li * 8;
        float4 u0 = *(const float4*)(up);
        float4 u1 = *(const float4*)(up + 4);
        float4 v0 = *(const float4*)(vp);
        float4 v1 = *(const float4*)(vp + 4);
        ur[p][0] = u0.x; ur[p][1] = u0.y; ur[p][2] = u0.z; ur[p][3] = u0.w;
        ur[p][4] = u1.x; ur[p][5] = u1.y; ur[p][6] = u1.z; ur[p][7] = u1.w;
        vr[p][0] = v0.x; vr[p][1] = v0.y; vr[p][2] = v0.z; vr[p][3] = v0.w;
        vr[p][4] = v1.x; vr[p][5] = v1.y; vr[p][6] = v1.z; vr[p][7] = v1.w;
    }
    const ush* wsb = Ws_bf + (size_t)b * SS * HH;
#pragma unroll
    for (int pass = 0; pass < 4; pass++) {
        int s = pass * 32 + wave * 4 + hi;
        float acc = 0.0f;
#pragma unroll
        for (int p = 0; p < 4; p++) {
            short8 rv = *(const short8*)(wsb + (size_t)s * HH + p * 128 + li * 8);
#pragma unroll
            for (int j = 0; j < 8; j++) {
                float e = bf2f((ush)rv[j]) + ur[p][j];
                acc += fmaxf(e, 0.0f) * vr[p][j];
            }
        }
#pragma unroll
        for (int off = 1; off < 16; off <<= 1) acc += __shfl_xor(acc, off);
        if (li == 0) a[s] = acc;
    }
    __syncthreads();
    if (wave == 0) {
        float s0v = a[lane], s1v = a[lane + 64];
        float m = wave_max(fmaxf(s0v, s1v));
        float e0 = expf(s0v - m), e1 = expf(s1v - m);
        float ssum = wave_sum(e0 + e1);
        float inv = 1.0f / ssum;
        a[lane] = e0 * inv;
        a[lane + 64] = e1 * inv;
    }
    __syncthreads();
    // ctx: wave w handles s = w*16..w*16+15; lane owns c-octet lane*8.
    float c8[8];
#pragma unroll
    for (int j = 0; j < 8; j++) c8[j] = 0.0f;
    const ush* ebt = enc_t + (size_t)b * SS * 512;
#pragma unroll
    for (int i = 0; i < 16; i++) {
        int s = wave * 16 + i;
        float as = a[s];
        short8 ev = *(const short8*)(ebt + (size_t)s * 512 + lane * 8);
#pragma unroll
        for (int j = 0; j < 8; j++) c8[j] += as * bf2f((ush)ev[j]);
    }
    *(float4*)(&part[wave][lane * 8])     = (float4){c8[0], c8[1], c8[2], c8[3]};
    *(float4*)(&part[wave][lane * 8 + 4]) = (float4){c8[4], c8[5], c8[6], c8[7]};
    __syncthreads();
    {
        float sum = 0.0f;
#pragma unroll
        for (int w = 0; w < 8; w++) sum += part[w][tid];
        ctx_bf[(size_t)b * CC + tid] = f2bf(sum);
    }
}

// ---------------------------------------------------------------------------
// Fused cls GEMM + log-softmax NLL. Grid 368 (16 items each), 256 thr.
__global__ __launch_bounds__(256) void cls_fused(const ush* __restrict__ ys,
                                                 const ush* __restrict__ wCls,
                                                 const float* __restrict__ cls_b,
                                                 const int* __restrict__ seq,
                                                 float* __restrict__ acc) {
    int tid = threadIdx.x;
    int wave = tid >> 6, lane = tid & 63;
    int quad = lane >> 4, l16 = lane & 15;
    int m0 = blockIdx.x * 16;
    f32x4 a4[4];
#pragma unroll
    for (int s = 0; s < 4; s++) a4[s] = (f32x4){0.f, 0.f, 0.f, 0.f};
    const ush* ap = ys + (size_t)(m0 + l16) * 512 + wave * 128 + quad * 8;
    const ush* bp = wCls + (size_t)l16 * 512 + wave * 128 + quad * 8;
#pragma unroll
    for (int ks = 0; ks < 4; ks++) {
        short8 av = *(const short8*)(ap + ks * 32);
#pragma unroll
        for (int s = 0; s < 4; s++) {
            short8 bv = *(const short8*)(bp + (size_t)s * 16 * 512 + ks * 32);
            a4[s] = __builtin_amdgcn_mfma_f32_16x16x32_bf16(av, bv, a4[s], 0, 0, 0);
        }
    }
    __shared__ float gbuf[4][16][64];
    __shared__ float red[8];
#pragma unroll
    for (int s = 0; s < 4; s++)
#pragma unroll
        for (int r = 0; r < 4; r++)
            gbuf[wave][quad * 4 + r][s * 16 + l16] = a4[s][r];
    __syncthreads();
    float lsum = 0.0f, lcnt = 0.0f;
#pragma unroll
    for (int ii = 0; ii < 4; ii++) {
        int mi = wave * 4 + ii;
        int item = m0 + mi;
        int t = item >> 8, b = item & 255;
        float v = gbuf[0][mi][lane] + gbuf[1][mi][lane] + gbuf[2][mi][lane] +
                  gbuf[3][mi][lane] + cls_b[lane];
        float mx = wave_max(v);
        float e = expf(v - mx);
        float ssum = wave_sum(e);
        int label = seq[b * LL + t + 1];
        float vl = __shfl(v, label);
        if (label > 0) {
            lsum += -(vl - mx - logf(ssum));
            lcnt += 1.0f;
        }
    }
    if (lane == 0) { red[wave] = lsum; red[4 + wave] = lcnt; }
    __syncthreads();
    if (tid == 0) {
        atomicAdd(&acc[0], red[0] + red[1] + red[2] + red[3]);
        atomicAdd(&acc[1], red[4] + red[5] + red[6] + red[7]);
    }
}

__global__ void final_kernel(const float* __restrict__ acc, float* __restrict__ out) {
    if (threadIdx.x == 0) out[0] = acc[0] / acc[1];
}

// ---------------------------------------------------------------------------
extern "C" void kernel_launch(void* const* d_in, const int* in_sizes, int n_in,
                              void* d_out, int out_size, void* d_ws, size_t ws_size,
                              hipStream_t stream) {
    const float* enc        = (const float*)d_in[0];
    const int*   seq        = (const int*)d_in[1];
    const float* embed_w    = (const float*)d_in[3];
    const float* init_state = (const float*)d_in[4];
    const float* attn_W_w   = (const float*)d_in[5];
    const float* attn_W_b   = (const float*)d_in[6];
    const float* attn_U_w   = (const float*)d_in[7];
    const float* attn_U_b   = (const float*)d_in[8];
    const float* attn_v_w   = (const float*)d_in[9];
    const float* fc_w       = (const float*)d_in[11];
    const float* fc_b       = (const float*)d_in[12];
    const float* cls_w      = (const float*)d_in[13];
    const float* cls_b      = (const float*)d_in[14];
    const float* g0_wih     = (const float*)d_in[15];
    const float* g0_whh     = (const float*)d_in[16];
    const float* g0_bih     = (const float*)d_in[17];
    const float* g0_bhh     = (const float*)d_in[18];
    const float* g1_wih     = (const float*)d_in[19];
    const float* g1_whh     = (const float*)d_in[20];
    const float* g1_bih     = (const float*)d_in[21];
    const float* g1_bhh     = (const float*)d_in[22];
    float* out = (float*)d_out;

    float* ws = (float*)d_ws;
    size_t o = 0;
    ush* Ws_bf   = (ush*)(ws + o); o += (size_t)BB * SS * HH / 2;
    ush* enc_t   = (ush*)(ws + o); o += (size_t)BB * CC * SS / 2;
    ush* ys_bf   = (ush*)(ws + o); o += (size_t)(LL - 1) * BB * HH / 2;
    ush* xall_bf = (ush*)(ws + o); o += (size_t)(LL - 1) * BB * HH / 2;
    // bf16 weights
    ush* wWb  = (ush*)(ws + o); o += 262144 / 2;
    ush* wU   = (ush*)(ws + o); o += 262144 / 2;
    ush* wFc  = (ush*)(ws + o); o += 524288 / 2;
    ush* wCls = (ush*)(ws + o); o += 32768 / 2;
    ush* wG0i = (ush*)(ws + o); o += 1572864 / 2;
    ush* wG0h = (ush*)(ws + o); o += 786432 / 2;
    ush* wG1i = (ush*)(ws + o); o += 786432 / 2;
    ush* wG1h = (ush*)(ws + o); o += 786432 / 2;
    // fp32 loop buffers
    float* Uo   = ws + o; o += (size_t)BB * HH;
    float* h0a  = ws + o; o += (size_t)BB * HH;
    float* h0b  = ws + o; o += (size_t)BB * HH;
    float* h1a  = ws + o; o += (size_t)BB * HH;
    float* h1b  = ws + o; o += (size_t)BB * HH;
    float* acc  = ws + o; o += 256;
    ush* h0a_bf = (ush*)(ws + o); o += (size_t)BB * HH / 2;
    ush* h0b_bf = (ush*)(ws + o); o += (size_t)BB * HH / 2;
    ush* h1a_bf = (ush*)(ws + o); o += (size_t)BB * HH / 2;
    ush* h1b_bf = (ush*)(ws + o); o += (size_t)BB * HH / 2;
    ush* y_bf   = (ush*)(ws + o); o += (size_t)BB * HH / 2;
    ush* ctx_bf = (ush*)(ws + o); o += (size_t)BB * CC / 2;

    init_kernel<<<512, 256, 0, stream>>>(init_state, h0a, h1a, h0a_bf, h1a_bf, acc);
    {
        CvArgs cv{};
        cv.src[0] = attn_W_w; cv.dst[0] = wWb;
        cv.src[1] = attn_U_w; cv.dst[1] = wU;
        cv.src[2] = fc_w;     cv.dst[2] = wFc;
        cv.src[3] = cls_w;    cv.dst[3] = wCls;
        cv.src[4] = g0_wih;   cv.dst[4] = wG0i;
        cv.src[5] = g0_whh;   cv.dst[5] = wG0h;
        cv.src[6] = g1_wih;   cv.dst[6] = wG1i;
        cv.src[7] = g1_whh;   cv.dst[7] = wG1h;
        cv.end[0] = 256;  cv.end[1] = 512;  cv.end[2] = 1024; cv.end[3] = 1056;
        cv.end[4] = 2592; cv.end[5] = 3360; cv.end[6] = 4128; cv.end[7] = 4896;
        conv_multi<<<4896, 256, 0, stream>>>(cv);
    }
    enc_conv<<<dim3(256, 4), 256, 0, stream>>>(enc, enc_t);
    gather_kernel<<<(LL - 1) * BB, 128, 0, stream>>>(embed_w, seq, xall_bf);
    ws_mfma<<<dim3(128, 8), 256, 0, stream>>>(enc, wWb, attn_W_b, Ws_bf);

    auto setw = [](GruArgs& a, int w, int e, const ush* xs, const ush* wb,
                   int wst, int nks, int slot) {
        a.xs[w][e] = xs; a.wb[w][e] = wb; a.wst[w][e] = wst;
        a.nks[w][e] = nks; a.slot[w][e] = slot;
    };
    auto gru0_args = [&](const ush* y, const ush* x, const ush* h0) {
        GruArgs a{};
        setw(a, 0, 0, y,        wG0i,                             1024, 16, 0);  // r <- y
        setw(a, 1, 0, x,        wG0i + 512,                       1024, 16, 1);  // r <- x
        setw(a, 2, 0, h0,       wG0h,                              512, 16, 2);  // r <- h
        setw(a, 3, 0, y,        wG0i + (size_t)512 * 1024,        1024, 16, 3);  // z <- y
        setw(a, 4, 0, x,        wG0i + (size_t)512 * 1024 + 512,  1024, 16, 4);  // z <- x
        setw(a, 5, 0, h0,       wG0h + (size_t)512 * 512,          512, 16, 5);  // z <- h
        setw(a, 6, 0, y,        wG0i + (size_t)1024 * 1024,       1024, 16, 6);  // ni <- y
        setw(a, 7, 0, x,        wG0i + (size_t)1024 * 1024 + 512, 1024, 16, 7);  // ni <- x
        // nh split into 4x 4-kstep quarters on waves 0-3 (crit path <= 20)
        setw(a, 0, 1, h0,       wG0h + (size_t)1024 * 512,         512,  4, 8);
        setw(a, 1, 1, h0 + 128, wG0h + (size_t)1024 * 512 + 128,   512,  4, 9);
        setw(a, 2, 1, h0 + 256, wG0h + (size_t)1024 * 512 + 256,   512,  4, 10);
        setw(a, 3, 1, h0 + 384, wG0h + (size_t)1024 * 512 + 384,   512,  4, 11);
        a.zmask = 0;
        return a;
    };
    auto gru1_args = [&](const ush* hl0, const ush* h1) {
        GruArgs a{};
        setw(a, 0, 0, hl0,       wG1i,                             512, 16, 0);  // r <- i
        setw(a, 1, 0, h1,        wG1h,                             512, 16, 1);  // r <- h
        setw(a, 2, 0, hl0,       wG1i + (size_t)512 * 512,         512, 16, 3);  // z <- i
        setw(a, 3, 0, h1,        wG1h + (size_t)512 * 512,         512, 16, 4);  // z <- h
        setw(a, 4, 0, hl0,       wG1i + (size_t)1024 * 512,        512,  8, 6);  // ni lo
        setw(a, 5, 0, hl0 + 256, wG1i + (size_t)1024 * 512 + 256,  512,  8, 7);  // ni hi
        setw(a, 6, 0, h1,        wG1h + (size_t)1024 * 512,        512,  8, 8);  // nh lo
        setw(a, 7, 0, h1 + 256,  wG1h + (size_t)1024 * 512 + 256,  512,  8, 9);  // nh hi
        a.zmask = (1 << 2) | (1 << 5) | (1 << 10) | (1 << 11);
        return a;
    };

    // ---- prologue: y0 = out_proj(attn(h1), h1)
    u_fused<<<512, 512, 0, stream>>>(h1a_bf, wU, attn_U_b, Uo);
    attn3<<<BB, 512, 0, stream>>>(Uo, attn_v_w, Ws_bf, enc_t, ctx_bf);
    fc_fused<<<512, 512, 0, stream>>>(ctx_bf, h1a_bf, wFc, fc_b, y_bf, nullptr);

    float* h0_in = h0a; float* h0_out = h0b;
    float* h1_in = h1a; float* h1_out = h1b;
    ush* h0_in_bf = h0a_bf; ush* h0_out_bf = h0b_bf;
    ush* h1_in_bf = h1a_bf; ush* h1_out_bf = h1b_bf;
    for (int t = 0; t < LL - 1; t++) {
        gru_fused<<<512, 512, 0, stream>>>(
            gru0_args(y_bf, xall_bf + (size_t)t * BB * HH, h0_in_bf),
            h0_in, g0_bih, g0_bhh, h0_out, h0_out_bf);
        gru_fused<<<512, 512, 0, stream>>>(
            gru1_args(h0_out_bf, h1_in_bf),
            h1_in, g1_bih, g1_bhh, h1_out, h1_out_bf);
        u_fused<<<512, 512, 0, stream>>>(h1_out_bf, wU, attn_U_b, Uo);
        attn3<<<BB, 512, 0, stream>>>(Uo, attn_v_w, Ws_bf, enc_t, ctx_bf);
        fc_fused<<<512, 512, 0, stream>>>(ctx_bf, h1_out_bf, wFc, fc_b,
                                          y_bf, ys_bf + (size_t)t * BB * HH);
        float* tmp;
        tmp = h0_in; h0_in = h0_out; h0_out = tmp;
        tmp = h1_in; h1_in = h1_out; h1_out = tmp;
        ush* tb;
        tb = h0_in_bf; h0_in_bf = h0_out_bf; h0_out_bf = tb;
        tb = h1_in_bf; h1_in_bf = h1_out_bf; h1_out_bf = tb;
    }

    cls_fused<<<368, 256, 0, stream>>>(ys_bf, wCls, cls_b, seq, acc);
    final_kernel<<<1, 1, 0, stream>>>(acc, out);
}

// Round 11
// 1339.629 us; speedup vs baseline: 1.1172x; 1.1172x over previous
//
#include <hip/hip_runtime.h>
#include <hip/hip_bf16.h>
#include <cstddef>

// Problem dims (fixed)
#define BB 256
#define CC 512
#define SS 128      // FH*FW = 8*16
#define HH 512
#define VV 64
#define LL 24       // sequence length; steps = 23

typedef unsigned short ush;
typedef __attribute__((ext_vector_type(8))) short short8;
typedef __attribute__((ext_vector_type(4))) float f32x4;

__device__ __forceinline__ float wave_sum(float v) {
#pragma unroll
    for (int off = 32; off > 0; off >>= 1) v += __shfl_xor(v, off);
    return v;
}
__device__ __forceinline__ float wave_max(float v) {
#pragma unroll
    for (int off = 32; off > 0; off >>= 1) v = fmaxf(v, __shfl_xor(v, off));
    return v;
}
__device__ __forceinline__ float sigm(float x) { return 1.0f / (1.0f + expf(-x)); }
__device__ __forceinline__ ush f2bf(float f) {
    unsigned u = __float_as_uint(f);
    u += 0x7FFFu + ((u >> 16) & 1u);
    return (ush)(u >> 16);
}
__device__ __forceinline__ float bf2f(ush b) {
    return __uint_as_float(((unsigned)b) << 16);
}
__device__ __forceinline__ unsigned pack2(float a, float b) {
    return (unsigned)f2bf(a) | ((unsigned)f2bf(b) << 16);
}

// XCD-pinned tile decode (round-8 proven, 256-block / 16m x 32n variant):
// consecutive block ids round-robin across the 8 XCDs, so give each XCD a
// fixed pair of n-tiles (64 cols) for ALL m-tiles. The per-XCD weight slice
// stays resident in that XCD's 4MiB L2 across the whole kernel.
__device__ __forceinline__ void xcd_tile(int bid, int& m0, int& n0) {
    int xcd = bid & 7;
    int j = bid >> 3;               // 0..31 within XCD
    int nt = xcd * 2 + (j & 1);     // 16 n-tiles of 32 cols
    int mt = j >> 1;                // 16 m-tiles of 16 rows
    m0 = mt * 16;
    n0 = nt * 32;
}

// ---------------------------------------------------------------------------
__global__ __launch_bounds__(256) void init_kernel(const float* __restrict__ init_state,
                                                   float* __restrict__ h0,
                                                   float* __restrict__ h1,
                                                   ush* __restrict__ h0b,
                                                   ush* __restrict__ h1b,
                                                   float* __restrict__ acc) {
    int idx = blockIdx.x * 256 + threadIdx.x;
    if (idx < BB * HH) {
        float a = init_state[idx & (HH - 1)];
        float b = init_state[HH + (idx & (HH - 1))];
        h0[idx] = a; h1[idx] = b;
        h0b[idx] = f2bf(a); h1b[idx] = f2bf(b);
    }
    if (idx < 2) acc[idx] = 0.0f;
}

// ---------------------------------------------------------------------------
// Multi-segment fp32->bf16 convert: all weight conversions in one launch.
struct CvArgs {
    const float* src[8];
    ush* dst[8];
    int end[8];    // cumulative block counts; each block = 256 float4
};
__global__ __launch_bounds__(256) void conv_multi(CvArgs A) {
    int blk = blockIdx.x;
    int s = 0;
    while (s < 7 && blk >= A.end[s]) s++;
    int base = s ? A.end[s - 1] : 0;
    int i = (blk - base) * 256 + threadIdx.x;
    float4 v = ((const float4*)A.src[s])[i];
    uint2 o;
    o.x = pack2(v.x, v.y);
    o.y = pack2(v.z, v.w);
    ((uint2*)A.dst[s])[i] = o;
}

// gather embeddings -> bf16: xall[(t*256+m)*512+:]
__global__ __launch_bounds__(128) void gather_kernel(const float* __restrict__ embed_w,
                                                     const int* __restrict__ seq,
                                                     ush* __restrict__ xall) {
    int item = blockIdx.x;           // t*256 + m
    int t = item >> 8, m = item & 255;
    int row = seq[m * LL + t];
    float4 v = ((const float4*)(embed_w + (size_t)row * HH))[threadIdx.x];
    uint2 o;
    o.x = pack2(v.x, v.y);
    o.y = pack2(v.z, v.w);
    ((uint2*)(xall + (size_t)item * HH))[threadIdx.x] = o;
}

// ---------------------------------------------------------------------------
// enc transpose+convert: enc fp32 [b][c=512][s=128] -> enc_t bf16 [b*128+s][c=512]
__global__ __launch_bounds__(256) void enc_conv(const float* __restrict__ enc,
                                                ush* __restrict__ enc_t) {
    int b = blockIdx.x, cg = blockIdx.y;
    int c0 = cg * 128;
    __shared__ ush tile[128][130];
    const float* src = enc + ((size_t)b * 512 + c0) * 128;
#pragma unroll
    for (int i = 0; i < 16; i++) {
        int lin = i * 256 + threadIdx.x;
        int cl = lin >> 5, s4 = lin & 31;
        float4 v = ((const float4*)(src + (size_t)cl * 128))[s4];
        tile[s4 * 4 + 0][cl] = f2bf(v.x);
        tile[s4 * 4 + 1][cl] = f2bf(v.y);
        tile[s4 * 4 + 2][cl] = f2bf(v.z);
        tile[s4 * 4 + 3][cl] = f2bf(v.w);
    }
    __syncthreads();
#pragma unroll
    for (int i = 0; i < 16; i++) {
        int lin = i * 256 + threadIdx.x;
        int sl = lin >> 5, c4 = lin & 31;
        ush a0 = tile[sl][c4 * 4 + 0], a1 = tile[sl][c4 * 4 + 1];
        ush a2 = tile[sl][c4 * 4 + 2], a3 = tile[sl][c4 * 4 + 3];
        uint2 o;
        o.x = (unsigned)a0 | ((unsigned)a1 << 16);
        o.y = (unsigned)a2 | ((unsigned)a3 << 16);
        ((uint2*)(enc_t + ((size_t)b * 128 + sl) * 512 + c0))[c4] = o;
    }
}

// ---------------------------------------------------------------------------
// Ws MFMA (r0 variant, 5x-proven fastest ~62us; do NOT replace with bf16-A
// variants — r7/r9 both regressed: this one is strided-BW-bound at 2.5TB/s
// and its many outstanding scalar loads self-hide latency).
// Block: 256m x 64n (4 waves x 64m). grid (128, 8).
__global__ __launch_bounds__(256) void ws_mfma(const float* __restrict__ enc,
                                               const ush* __restrict__ Wb,
                                               const float* __restrict__ bias,
                                               ush* __restrict__ Ws_bf) {
    int tid = threadIdx.x;
    int wave = tid >> 6, lane = tid & 63;
    int quad = lane >> 4, l16 = lane & 15;
    int m0 = blockIdx.x * 256 + wave * 64;
    int n0 = blockIdx.y * 64;
    int b = m0 >> 7;
    int s_base = m0 & 127;
    const float* eb = enc + (size_t)b * CC * SS;
    const ush* wp = Wb + (size_t)(n0 + l16) * 512 + quad * 8;
    f32x4 acc[4][4];
#pragma unroll
    for (int f = 0; f < 4; f++)
#pragma unroll
        for (int s = 0; s < 4; s++) acc[f][s] = (f32x4){0.f, 0.f, 0.f, 0.f};
    for (int k0 = 0; k0 < 512; k0 += 32) {
        short8 af[4], bfr[4];
#pragma unroll
        for (int f = 0; f < 4; f++) {
            int s = s_base + f * 16 + l16;
#pragma unroll
            for (int j = 0; j < 8; j++) {
                float v = eb[(size_t)(k0 + quad * 8 + j) * SS + s];
                af[f][j] = (short)f2bf(v);
            }
        }
#pragma unroll
        for (int s = 0; s < 4; s++)
            bfr[s] = *(const short8*)(wp + (size_t)s * 16 * 512 + k0);
#pragma unroll
        for (int f = 0; f < 4; f++)
#pragma unroll
            for (int s = 0; s < 4; s++)
                acc[f][s] = __builtin_amdgcn_mfma_f32_16x16x32_bf16(af[f], bfr[s], acc[f][s], 0, 0, 0);
    }
#pragma unroll
    for (int f = 0; f < 4; f++)
#pragma unroll
        for (int s = 0; s < 4; s++)
#pragma unroll
            for (int r = 0; r < 4; r++) {
                int m = m0 + f * 16 + quad * 4 + r;
                int n = n0 + s * 16 + l16;
                Ws_bf[(size_t)m * HH + n] = f2bf(acc[f][s][r] + bias[n]);
            }
}

// ---------------------------------------------------------------------------
// Prefetched MFMA pipeline over one K-segment (NSTEP k-steps of 32).
// Ring depth 8 for NSTEP>=8 (r9-proven loop gain). 2 n-fragments (32 cols).
// A row stride fixed 512 (folded by caller).
template <int NSTEP>
__device__ __forceinline__ void segk(const ush* __restrict__ ap,
                                     const ush* __restrict__ bp,
                                     size_t wofs, f32x4& a0, f32x4& a1) {
    constexpr int RING = NSTEP >= 8 ? 8 : (NSTEP < 4 ? NSTEP : 4);
    short8 as[RING], bs0[RING], bs1[RING];
#pragma unroll
    for (int i = 0; i < RING; i++) {
        as[i]  = *(const short8*)(ap + 32 * i);
        bs0[i] = *(const short8*)(bp + 32 * i);
        bs1[i] = *(const short8*)(bp + wofs + 32 * i);
    }
#pragma unroll
    for (int i = 0; i < NSTEP; i++) {
        const int sl = i & (RING - 1);
        a0 = __builtin_amdgcn_mfma_f32_16x16x32_bf16(as[sl], bs0[sl], a0, 0, 0, 0);
        a1 = __builtin_amdgcn_mfma_f32_16x16x32_bf16(as[sl], bs1[sl], a1, 0, 0, 0);
        if (i + RING < NSTEP) {
            as[sl]  = *(const short8*)(ap + 32 * (i + RING));
            bs0[sl] = *(const short8*)(bp + 32 * (i + RING));
            bs1[sl] = *(const short8*)(bp + wofs + 32 * (i + RING));
        }
    }
}

// ---------------------------------------------------------------------------
// Fused GRU: 512 threads, 8 waves; each wave up to 2 (segment,slot) entries.
// 12 LDS slots: r = s0+s1+s2, z = s3+s4+s5, n_i = s6+s7, n_h = s8+s9+s10+s11.
// 1D grid 256 with XCD-pinned (m0,n0) decode.
struct GruArgs {
    const ush* xs[8][2];
    const ush* wb[8][2];
    int wst[8][2];
    int nks[8][2];     // 0, 4, 8, or 16 k-steps
    int slot[8][2];
    int zmask;         // slots to zero-fill
};

__global__ __launch_bounds__(512) void gru_fused(GruArgs A,
                                                 const float* __restrict__ h_prev,
                                                 const float* __restrict__ bih,
                                                 const float* __restrict__ bhh,
                                                 float* __restrict__ h_out,
                                                 ush* __restrict__ h_out_bf) {
    int tid = threadIdx.x;
    int wave = __builtin_amdgcn_readfirstlane(tid >> 6);
    int lane = tid & 63, quad = lane >> 4, l16 = lane & 15;
    int m0, n0;
    xcd_tile(blockIdx.x, m0, n0);
    __shared__ float gbuf[12][16][32];
    if (A.zmask) {
        int mi = (tid >> 5) & 15, ni = tid & 31;
#pragma unroll
        for (int s = 0; s < 12; s++)
            if ((A.zmask >> s) & 1) gbuf[s][mi][ni] = 0.0f;
    }
    for (int e = 0; e < 2; e++) {
        int nks = A.nks[wave][e];
        if (nks == 0) continue;
        f32x4 a0 = (f32x4){0.f, 0.f, 0.f, 0.f};
        f32x4 a1 = (f32x4){0.f, 0.f, 0.f, 0.f};
        int wst = A.wst[wave][e];
        const ush* ap = A.xs[wave][e] + (size_t)(m0 + l16) * 512 + quad * 8;
        const ush* bp = A.wb[wave][e] + (size_t)(n0 + l16) * wst + quad * 8;
        size_t wofs = (size_t)16 * wst;
        if (nks == 16)     segk<16>(ap, bp, wofs, a0, a1);
        else if (nks == 8) segk<8>(ap, bp, wofs, a0, a1);
        else               segk<4>(ap, bp, wofs, a0, a1);
        int sl = A.slot[wave][e];
#pragma unroll
        for (int r = 0; r < 4; r++) {
            gbuf[sl][quad * 4 + r][l16]      = a0[r];
            gbuf[sl][quad * 4 + r][16 + l16] = a1[r];
        }
    }
    __syncthreads();
    {
        int mi = tid >> 5, ni = tid & 31;
        int n = n0 + ni;
        size_t off = (size_t)(m0 + mi) * HH + n;
        float r  = sigm(gbuf[0][mi][ni] + gbuf[1][mi][ni] + gbuf[2][mi][ni] +
                        bih[n] + bhh[n]);
        float zf = sigm(gbuf[3][mi][ni] + gbuf[4][mi][ni] + gbuf[5][mi][ni] +
                        bih[512 + n] + bhh[512 + n]);
        float na = tanhf(gbuf[6][mi][ni] + gbuf[7][mi][ni] + bih[1024 + n] +
                         r * (gbuf[8][mi][ni] + gbuf[9][mi][ni] +
                              gbuf[10][mi][ni] + gbuf[11][mi][ni] + bhh[1024 + n]));
        float hp = h_prev[off];
        float ho = (1.0f - zf) * na + zf * hp;
        h_out[off] = ho;
        h_out_bf[off] = f2bf(ho);
    }
}

// ---------------------------------------------------------------------------
// Fused fc: y = relu([ctx|h] @ fc_w.T + b). 512 thr, 8 waves x K=128 each.
// 1D grid 256 with XCD-pinned decode.
__global__ __launch_bounds__(512) void fc_fused(const ush* __restrict__ ctx,
                                                const ush* __restrict__ h,
                                                const ush* __restrict__ wFc,
                                                const float* __restrict__ bias,
                                                ush* __restrict__ y,
                                                ush* __restrict__ ys) {
    int tid = threadIdx.x;
    int wave = __builtin_amdgcn_readfirstlane(tid >> 6);
    int lane = tid & 63, quad = lane >> 4, l16 = lane & 15;
    int m0, n0;
    xcd_tile(blockIdx.x, m0, n0);
    const ush* X = (wave < 4) ? ctx : h;
    int q = wave & 3;
    f32x4 a0 = (f32x4){0.f, 0.f, 0.f, 0.f};
    f32x4 a1 = (f32x4){0.f, 0.f, 0.f, 0.f};
    const ush* ap = X + (size_t)(m0 + l16) * 512 + q * 128 + quad * 8;
    const ush* bp = wFc + (size_t)(n0 + l16) * 1024 + (wave >= 4 ? 512 : 0) + q * 128 + quad * 8;
    segk<4>(ap, bp, (size_t)16 * 1024, a0, a1);
    __shared__ float gbuf[8][16][32];
#pragma unroll
    for (int r = 0; r < 4; r++) {
        gbuf[wave][quad * 4 + r][l16]      = a0[r];
        gbuf[wave][quad * 4 + r][16 + l16] = a1[r];
    }
    __syncthreads();
    {
        int mi = tid >> 5, ni = tid & 31;
        int n = n0 + ni;
        float v = bias[n];
#pragma unroll
        for (int w = 0; w < 8; w++) v += gbuf[w][mi][ni];
        v = fmaxf(v, 0.0f);
        ush bb = f2bf(v);
        size_t off = (size_t)(m0 + mi) * HH + n;
        y[off] = bb;
        if (ys) ys[off] = bb;
    }
}

// ---------------------------------------------------------------------------
// Fused u: u = h @ U.T + Ub (fp32 out). 512 thr, 8 waves x K=64 each.
// 1D grid 256 with XCD-pinned decode.
__global__ __launch_bounds__(512) void u_fused(const ush* __restrict__ h,
                                               const ush* __restrict__ wU,
                                               const float* __restrict__ Ub,
                                               float* __restrict__ Uo) {
    int tid = threadIdx.x;
    int wave = __builtin_amdgcn_readfirstlane(tid >> 6);
    int lane = tid & 63, quad = lane >> 4, l16 = lane & 15;
    int m0, n0;
    xcd_tile(blockIdx.x, m0, n0);
    f32x4 a0 = (f32x4){0.f, 0.f, 0.f, 0.f};
    f32x4 a1 = (f32x4){0.f, 0.f, 0.f, 0.f};
    const ush* ap = h + (size_t)(m0 + l16) * 512 + wave * 64 + quad * 8;
    const ush* bp = wU + (size_t)(n0 + l16) * 512 + wave * 64 + quad * 8;
    segk<2>(ap, bp, (size_t)16 * 512, a0, a1);
    __shared__ float gbuf[8][16][32];
#pragma unroll
    for (int r = 0; r < 4; r++) {
        gbuf[wave][quad * 4 + r][l16]      = a0[r];
        gbuf[wave][quad * 4 + r][16 + l16] = a1[r];
    }
    __syncthreads();
    {
        int mi = tid >> 5, ni = tid & 31;
        int n = n0 + ni;
        float v = Ub[n];
#pragma unroll
        for (int w = 0; w < 8; w++) v += gbuf[w][mi][ni];
        Uo[(size_t)(m0 + mi) * HH + n] = v;
    }
}

// ---------------------------------------------------------------------------
// Attention v3 (round-2 proven): 512 threads/block, one block per batch item.
__global__ __launch_bounds__(512) void attn3(const float* __restrict__ u,
                                             const float* __restrict__ vw,
                                             const ush* __restrict__ Ws_bf,
                                             const ush* __restrict__ enc_t,
                                             ush* __restrict__ ctx_bf) {
    int b = blockIdx.x;
    int tid = threadIdx.x;
    int wave = tid >> 6, lane = tid & 63;
    int hi = lane >> 4, li = lane & 15;
    __shared__ float a[SS];
    __shared__ float part[8][512];

    float ur[4][8], vr[4][8];
#pragma unroll
    for (int p = 0; p < 4; p++) {
        const float* up = u + (size_t)b * HH + p * 128 + li * 8;
        const float* vp = vw + p * 128 + li * 8;
        float4 u0 = *(const float4*)(up);
        float4 u1 = *(const float4*)(up + 4);
        float4 v0 = *(const float4*)(vp);
        float4 v1 = *(const float4*)(vp + 4);
        ur[p][0] = u0.x; ur[p][1] = u0.y; ur[p][2] = u0.z; ur[p][3] = u0.w;
        ur[p][4] = u1.x; ur[p][5] = u1.y; ur[p][6] = u1.z; ur[p][7] = u1.w;
        vr[p][0] = v0.x; vr[p][1] = v0.y; vr[p][2] = v0.z; vr[p][3] = v0.w;
        vr[p][4] = v1.x; vr[p][5] = v1.y; vr[p][6] = v1.z; vr[p][7] = v1.w;
    }
    const ush* wsb = Ws_bf + (size_t)b * SS * HH;
#pragma unroll
    for (int pass = 0; pass < 4; pass++) {
        int s = pass * 32 + wave * 4 + hi;
        float acc = 0.0f;
#pragma unroll
        for (int p = 0; p < 4; p++) {
            short8 rv = *(const short8*)(wsb + (size_t)s * HH + p * 128 + li * 8);
#pragma unroll
            for (int j = 0; j < 8; j++) {
                float e = bf2f((ush)rv[j]) + ur[p][j];
                acc += fmaxf(e, 0.0f) * vr[p][j];
            }
        }
#pragma unroll
        for (int off = 1; off < 16; off <<= 1) acc += __shfl_xor(acc, off);
        if (li == 0) a[s] = acc;
    }
    __syncthreads();
    if (wave == 0) {
        float s0v = a[lane], s1v = a[lane + 64];
        float m = wave_max(fmaxf(s0v, s1v));
        float e0 = expf(s0v - m), e1 = expf(s1v - m);
        float ssum = wave_sum(e0 + e1);
        float inv = 1.0f / ssum;
        a[lane] = e0 * inv;
        a[lane + 64] = e1 * inv;
    }
    __syncthreads();
    // ctx: wave w handles s = w*16..w*16+15; lane owns c-octet lane*8.
    float c8[8];
#pragma unroll
    for (int j = 0; j < 8; j++) c8[j] = 0.0f;
    const ush* ebt = enc_t + (size_t)b * SS * 512;
#pragma unroll
    for (int i = 0; i < 16; i++) {
        int s = wave * 16 + i;
        float as = a[s];
        short8 ev = *(const short8*)(ebt + (size_t)s * 512 + lane * 8);
#pragma unroll
        for (int j = 0; j < 8; j++) c8[j] += as * bf2f((ush)ev[j]);
    }
    *(float4*)(&part[wave][lane * 8])     = (float4){c8[0], c8[1], c8[2], c8[3]};
    *(float4*)(&part[wave][lane * 8 + 4]) = (float4){c8[4], c8[5], c8[6], c8[7]};
    __syncthreads();
    {
        float sum = 0.0f;
#pragma unroll
        for (int w = 0; w < 8; w++) sum += part[w][tid];
        ctx_bf[(size_t)b * CC + tid] = f2bf(sum);
    }
}

// ---------------------------------------------------------------------------
// Fused cls GEMM + log-softmax NLL. Grid 368 (16 items each), 256 thr.
__global__ __launch_bounds__(256) void cls_fused(const ush* __restrict__ ys,
                                                 const ush* __restrict__ wCls,
                                                 const float* __restrict__ cls_b,
                                                 const int* __restrict__ seq,
                                                 float* __restrict__ acc) {
    int tid = threadIdx.x;
    int wave = tid >> 6, lane = tid & 63;
    int quad = lane >> 4, l16 = lane & 15;
    int m0 = blockIdx.x * 16;
    f32x4 a4[4];
#pragma unroll
    for (int s = 0; s < 4; s++) a4[s] = (f32x4){0.f, 0.f, 0.f, 0.f};
    const ush* ap = ys + (size_t)(m0 + l16) * 512 + wave * 128 + quad * 8;
    const ush* bp = wCls + (size_t)l16 * 512 + wave * 128 + quad * 8;
#pragma unroll
    for (int ks = 0; ks < 4; ks++) {
        short8 av = *(const short8*)(ap + ks * 32);
#pragma unroll
        for (int s = 0; s < 4; s++) {
            short8 bv = *(const short8*)(bp + (size_t)s * 16 * 512 + ks * 32);
            a4[s] = __builtin_amdgcn_mfma_f32_16x16x32_bf16(av, bv, a4[s], 0, 0, 0);
        }
    }
    __shared__ float gbuf[4][16][64];
    __shared__ float red[8];
#pragma unroll
    for (int s = 0; s < 4; s++)
#pragma unroll
        for (int r = 0; r < 4; r++)
            gbuf[wave][quad * 4 + r][s * 16 + l16] = a4[s][r];
    __syncthreads();
    float lsum = 0.0f, lcnt = 0.0f;
#pragma unroll
    for (int ii = 0; ii < 4; ii++) {
        int mi = wave * 4 + ii;
        int item = m0 + mi;
        int t = item >> 8, b = item & 255;
        float v = gbuf[0][mi][lane] + gbuf[1][mi][lane] + gbuf[2][mi][lane] +
                  gbuf[3][mi][lane] + cls_b[lane];
        float mx = wave_max(v);
        float e = expf(v - mx);
        float ssum = wave_sum(e);
        int label = seq[b * LL + t + 1];
        float vl = __shfl(v, label);
        if (label > 0) {
            lsum += -(vl - mx - logf(ssum));
            lcnt += 1.0f;
        }
    }
    if (lane == 0) { red[wave] = lsum; red[4 + wave] = lcnt; }
    __syncthreads();
    if (tid == 0) {
        atomicAdd(&acc[0], red[0] + red[1] + red[2] + red[3]);
        atomicAdd(&acc[1], red[4] + red[5] + red[6] + red[7]);
    }
}

__global__ void final_kernel(const float* __restrict__ acc, float* __restrict__ out) {
    if (threadIdx.x == 0) out[0] = acc[0] / acc[1];
}

// ---------------------------------------------------------------------------
extern "C" void kernel_launch(void* const* d_in, const int* in_sizes, int n_in,
                              void* d_out, int out_size, void* d_ws, size_t ws_size,
                              hipStream_t stream) {
    const float* enc        = (const float*)d_in[0];
    const int*   seq        = (const int*)d_in[1];
    const float* embed_w    = (const float*)d_in[3];
    const float* init_state = (const float*)d_in[4];
    const float* attn_W_w   = (const float*)d_in[5];
    const float* attn_W_b   = (const float*)d_in[6];
    const float* attn_U_w   = (const float*)d_in[7];
    const float* attn_U_b   = (const float*)d_in[8];
    const float* attn_v_w   = (const float*)d_in[9];
    const float* fc_w       = (const float*)d_in[11];
    const float* fc_b       = (const float*)d_in[12];
    const float* cls_w      = (const float*)d_in[13];
    const float* cls_b      = (const float*)d_in[14];
    const float* g0_wih     = (const float*)d_in[15];
    const float* g0_whh     = (const float*)d_in[16];
    const float* g0_bih     = (const float*)d_in[17];
    const float* g0_bhh     = (const float*)d_in[18];
    const float* g1_wih     = (const float*)d_in[19];
    const float* g1_whh     = (const float*)d_in[20];
    const float* g1_bih     = (const float*)d_in[21];
    const float* g1_bhh     = (const float*)d_in[22];
    float* out = (float*)d_out;

    float* ws = (float*)d_ws;
    size_t o = 0;
    ush* Ws_bf   = (ush*)(ws + o); o += (size_t)BB * SS * HH / 2;
    ush* enc_t   = (ush*)(ws + o); o += (size_t)BB * CC * SS / 2;
    ush* ys_bf   = (ush*)(ws + o); o += (size_t)(LL - 1) * BB * HH / 2;
    ush* xall_bf = (ush*)(ws + o); o += (size_t)(LL - 1) * BB * HH / 2;
    // bf16 weights
    ush* wWb  = (ush*)(ws + o); o += 262144 / 2;
    ush* wU   = (ush*)(ws + o); o += 262144 / 2;
    ush* wFc  = (ush*)(ws + o); o += 524288 / 2;
    ush* wCls = (ush*)(ws + o); o += 32768 / 2;
    ush* wG0i = (ush*)(ws + o); o += 1572864 / 2;
    ush* wG0h = (ush*)(ws + o); o += 786432 / 2;
    ush* wG1i = (ush*)(ws + o); o += 786432 / 2;
    ush* wG1h = (ush*)(ws + o); o += 786432 / 2;
    // fp32 loop buffers
    float* Uo   = ws + o; o += (size_t)BB * HH;
    float* h0a  = ws + o; o += (size_t)BB * HH;
    float* h0b  = ws + o; o += (size_t)BB * HH;
    float* h1a  = ws + o; o += (size_t)BB * HH;
    float* h1b  = ws + o; o += (size_t)BB * HH;
    float* acc  = ws + o; o += 256;
    ush* h0a_bf = (ush*)(ws + o); o += (size_t)BB * HH / 2;
    ush* h0b_bf = (ush*)(ws + o); o += (size_t)BB * HH / 2;
    ush* h1a_bf = (ush*)(ws + o); o += (size_t)BB * HH / 2;
    ush* h1b_bf = (ush*)(ws + o); o += (size_t)BB * HH / 2;
    ush* y_bf   = (ush*)(ws + o); o += (size_t)BB * HH / 2;
    ush* ctx_bf = (ush*)(ws + o); o += (size_t)BB * CC / 2;

    init_kernel<<<512, 256, 0, stream>>>(init_state, h0a, h1a, h0a_bf, h1a_bf, acc);
    {
        CvArgs cv{};
        cv.src[0] = attn_W_w; cv.dst[0] = wWb;
        cv.src[1] = attn_U_w; cv.dst[1] = wU;
        cv.src[2] = fc_w;     cv.dst[2] = wFc;
        cv.src[3] = cls_w;    cv.dst[3] = wCls;
        cv.src[4] = g0_wih;   cv.dst[4] = wG0i;
        cv.src[5] = g0_whh;   cv.dst[5] = wG0h;
        cv.src[6] = g1_wih;   cv.dst[6] = wG1i;
        cv.src[7] = g1_whh;   cv.dst[7] = wG1h;
        cv.end[0] = 256;  cv.end[1] = 512;  cv.end[2] = 1024; cv.end[3] = 1056;
        cv.end[4] = 2592; cv.end[5] = 3360; cv.end[6] = 4128; cv.end[7] = 4896;
        conv_multi<<<4896, 256, 0, stream>>>(cv);
    }
    enc_conv<<<dim3(256, 4), 256, 0, stream>>>(enc, enc_t);
    gather_kernel<<<(LL - 1) * BB, 128, 0, stream>>>(embed_w, seq, xall_bf);
    ws_mfma<<<dim3(128, 8), 256, 0, stream>>>(enc, wWb, attn_W_b, Ws_bf);

    auto setw = [](GruArgs& a, int w, int e, const ush* xs, const ush* wb,
                   int wst, int nks, int slot) {
        a.xs[w][e] = xs; a.wb[w][e] = wb; a.wst[w][e] = wst;
        a.nks[w][e] = nks; a.slot[w][e] = slot;
    };
    auto gru0_args = [&](const ush* y, const ush* x, const ush* h0) {
        GruArgs a{};
        setw(a, 0, 0, y,        wG0i,                             1024, 16, 0);  // r <- y
        setw(a, 1, 0, x,        wG0i + 512,                       1024, 16, 1);  // r <- x
        setw(a, 2, 0, h0,       wG0h,                              512, 16, 2);  // r <- h
        setw(a, 3, 0, y,        wG0i + (size_t)512 * 1024,        1024, 16, 3);  // z <- y
        setw(a, 4, 0, x,        wG0i + (size_t)512 * 1024 + 512,  1024, 16, 4);  // z <- x
        setw(a, 5, 0, h0,       wG0h + (size_t)512 * 512,          512, 16, 5);  // z <- h
        setw(a, 6, 0, y,        wG0i + (size_t)1024 * 1024,       1024, 16, 6);  // ni <- y
        setw(a, 7, 0, x,        wG0i + (size_t)1024 * 1024 + 512, 1024, 16, 7);  // ni <- x
        // nh split into 4x 4-kstep quarters on waves 0-3 (crit path <= 20)
        setw(a, 0, 1, h0,       wG0h + (size_t)1024 * 512,         512,  4, 8);
        setw(a, 1, 1, h0 + 128, wG0h + (size_t)1024 * 512 + 128,   512,  4, 9);
        setw(a, 2, 1, h0 + 256, wG0h + (size_t)1024 * 512 + 256,   512,  4, 10);
        setw(a, 3, 1, h0 + 384, wG0h + (size_t)1024 * 512 + 384,   512,  4, 11);
        a.zmask = 0;
        return a;
    };
    auto gru1_args = [&](const ush* hl0, const ush* h1) {
        GruArgs a{};
        setw(a, 0, 0, hl0,       wG1i,                             512, 16, 0);  // r <- i
        setw(a, 1, 0, h1,        wG1h,                             512, 16, 1);  // r <- h
        setw(a, 2, 0, hl0,       wG1i + (size_t)512 * 512,         512, 16, 3);  // z <- i
        setw(a, 3, 0, h1,        wG1h + (size_t)512 * 512,         512, 16, 4);  // z <- h
        setw(a, 4, 0, hl0,       wG1i + (size_t)1024 * 512,        512,  8, 6);  // ni lo
        setw(a, 5, 0, hl0 + 256, wG1i + (size_t)1024 * 512 + 256,  512,  8, 7);  // ni hi
        setw(a, 6, 0, h1,        wG1h + (size_t)1024 * 512,        512,  8, 8);  // nh lo
        setw(a, 7, 0, h1 + 256,  wG1h + (size_t)1024 * 512 + 256,  512,  8, 9);  // nh hi
        a.zmask = (1 << 2) | (1 << 5) | (1 << 10) | (1 << 11);
        return a;
    };

    // ---- prologue: y0 = out_proj(attn(h1), h1)
    u_fused<<<256, 512, 0, stream>>>(h1a_bf, wU, attn_U_b, Uo);
    attn3<<<BB, 512, 0, stream>>>(Uo, attn_v_w, Ws_bf, enc_t, ctx_bf);
    fc_fused<<<256, 512, 0, stream>>>(ctx_bf, h1a_bf, wFc, fc_b, y_bf, nullptr);

    float* h0_in = h0a; float* h0_out = h0b;
    float* h1_in = h1a; float* h1_out = h1b;
    ush* h0_in_bf = h0a_bf; ush* h0_out_bf = h0b_bf;
    ush* h1_in_bf = h1a_bf; ush* h1_out_bf = h1b_bf;
    for (int t = 0; t < LL - 1; t++) {
        gru_fused<<<256, 512, 0, stream>>>(
            gru0_args(y_bf, xall_bf + (size_t)t * BB * HH, h0_in_bf),
            h0_in, g0_bih, g0_bhh, h0_out, h0_out_bf);
        gru_fused<<<256, 512, 0, stream>>>(
            gru1_args(h0_out_bf, h1_in_bf),
            h1_in, g1_bih, g1_bhh, h1_out, h1_out_bf);
        u_fused<<<256, 512, 0, stream>>>(h1_out_bf, wU, attn_U_b, Uo);
        attn3<<<BB, 512, 0, stream>>>(Uo, attn_v_w, Ws_bf, enc_t, ctx_bf);
        fc_fused<<<256, 512, 0, stream>>>(ctx_bf, h1_out_bf, wFc, fc_b,
                                          y_bf, ys_bf + (size_t)t * BB * HH);
        float* tmp;
        tmp = h0_in; h0_in = h0_out; h0_out = tmp;
        tmp = h1_in; h1_in = h1_out; h1_out = tmp;
        ush* tb;
        tb = h0_in_bf; h0_in_bf = h0_out_bf; h0_out_bf = tb;
        tb = h1_in_bf; h1_in_bf = h1_out_bf; h1_out_bf = tb;
    }

    cls_fused<<<368, 256, 0, stream>>>(ys_bf, wCls, cls_b, seq, acc);
    final_kernel<<<1, 1, 0, stream>>>(acc, out);
}